// Round 3
// baseline (285.229 us; speedup 1.0000x reference)
//
#include <hip/hip_runtime.h>
#include <hip/hip_bf16.h>

#define BB 4
#define LL 2048
#define DD 512
#define DKK 256

typedef __bf16 bf16;
typedef __bf16 bf16x4 __attribute__((ext_vector_type(4)));
typedef __bf16 bf16x8 __attribute__((ext_vector_type(8)));
typedef float f32x4 __attribute__((ext_vector_type(4)));

__device__ __forceinline__ void async_ld16(const bf16* g, bf16* l) {
    __builtin_amdgcn_global_load_lds(
        (const __attribute__((address_space(1))) void*)g,
        (__attribute__((address_space(3))) void*)l, 16, 0, 0);
}

// fused bf16 conversion of the three [B,L,D] activations (one launch)
__global__ void conv3_f32_bf16(const float* __restrict__ a, const float* __restrict__ bq,
                               const float* __restrict__ c,
                               bf16* __restrict__ oa, bf16* __restrict__ ob,
                               bf16* __restrict__ oc, int n4) {
    const float* in = (blockIdx.y == 0) ? a : (blockIdx.y == 1) ? bq : c;
    bf16* out = (blockIdx.y == 0) ? oa : (blockIdx.y == 1) ? ob : oc;
    int i = blockIdx.x * 256 + threadIdx.x;
    if (i < n4) {
        f32x4 v = *(const f32x4*)(in + (size_t)i * 4);
        bf16x4 o;
        #pragma unroll
        for (int j = 0; j < 4; ++j) o[j] = (bf16)v[j];
        *(bf16x4*)(out + (size_t)i * 4) = o;
    }
}

__global__ void conv_f32_bf16v(const float* __restrict__ in, bf16* __restrict__ out, int n4) {
    int i = blockIdx.x * 256 + threadIdx.x;
    if (i < n4) {
        f32x4 v = *(const f32x4*)(in + (size_t)i * 4);
        bf16x4 o;
        #pragma unroll
        for (int j = 0; j < 4; ++j) o[j] = (bf16)v[j];
        *(bf16x4*)(out + (size_t)i * 4) = o;
    }
}

__global__ void transpose_f32_bf16(const float* __restrict__ in, bf16* __restrict__ out,
                                   int R, int C) {
    int idx = blockIdx.x * 256 + threadIdx.x;
    if (idx < R * C) {
        int r = idx / C, c = idx % C;
        out[(size_t)c * R + r] = (bf16)in[idx];
    }
}

// 64x64-tile bf16 transpose: in [R][C] -> out [C][R], coalesced both sides.
__global__ void transpose_bf16_tile(const bf16* __restrict__ in, bf16* __restrict__ out,
                                    int R, int C) {
    __shared__ bf16 t[64][72];
    int tcx = C >> 6;
    int bx = blockIdx.x % tcx, by = blockIdx.x / tcx;
    int r = threadIdx.x >> 2, cc = (threadIdx.x & 3) * 16;
    const bf16* src = in + (size_t)(by * 64 + r) * C + bx * 64 + cc;
    bf16x8 v0 = *(const bf16x8*)src;
    bf16x8 v1 = *(const bf16x8*)(src + 8);
    #pragma unroll
    for (int u = 0; u < 8; ++u) { t[cc + u][r] = v0[u]; t[cc + 8 + u][r] = v1[u]; }
    __syncthreads();
    bf16* dst = out + (size_t)(bx * 64 + r) * R + by * 64 + cc;
    *(bf16x8*)dst = *(const bf16x8*)&t[r][cc];
    *(bf16x8*)(dst + 8) = *(const bf16x8*)&t[r][cc + 8];
}

// Unified bf16 GEMM, m97-style: C[m][n] = sum_k A[m][k]*B[n][k].  128x128 tile,
// 4 waves (each 64x64 = 4x4 acc).  A and B staged direct-to-LDS via
// global_load_lds(16B) with parity-rotation swizzle.  bStride lets blockIdx.y
// batch over different B operands (Q+K fused launch).
// SKEW=1: scatter-store into skewed Srel layout.
template <int SKEW>
__launch_bounds__(256, 2)
__global__ void gemm128(const bf16* __restrict__ A, const bf16* __restrict__ B,
                        bf16* __restrict__ C, int N, int K,
                        long aStride, long bStride, long cStride)
{
    __shared__ bf16 Als[128 * 32];
    __shared__ bf16 Bls[128 * 32];

    int tid  = threadIdx.x;
    int lane = tid & 63;
    int wid  = tid >> 6;
    int l15  = lane & 15;
    int quad = lane >> 4;
    int nb = N >> 7;
    int gx = blockIdx.x % nb;
    int gy = blockIdx.x / nb;

    const bf16* Ab = A + (size_t)blockIdx.y * aStride + (size_t)gy * 128 * K;
    const bf16* Bb = B + (size_t)blockIdx.y * bStride + (size_t)gx * 128 * K;

    int rl = lane >> 2;     // staging: row within 16-row inst
    int sl = lane & 3;      // staging: slot
    int half = wid & 1;     // waves 0/2: rows 0-63; waves 1/3: rows 64-127
    const bf16* gsrc = (wid < 2) ? Ab : Bb;
    bf16* ldst = (wid < 2) ? Als : Bls;

    f32x4 acc[4][4];
    #pragma unroll
    for (int i = 0; i < 4; ++i)
        #pragma unroll
        for (int j = 0; j < 4; ++j) acc[i][j] = 0;

    for (int k0 = 0; k0 < K; k0 += 32) {
        #pragma unroll
        for (int u = 0; u < 4; ++u) {
            int inst = half * 4 + u;
            int row  = inst * 16 + rl;
            int c    = (sl - (row >> 1)) & 3;
            async_ld16(gsrc + (size_t)row * K + k0 + c * 8, ldst + inst * 512);
        }
        __syncthreads();   // drains vmcnt(0): staging complete
        bf16x8 fA[4], fB[4];
        #pragma unroll
        for (int rt = 0; rt < 4; ++rt) {
            int row = (wid & 1) * 64 + rt * 16 + l15;
            int s   = (quad + (row >> 1)) & 3;
            fA[rt] = *(const bf16x8*)&Als[row * 32 + s * 8];
        }
        #pragma unroll
        for (int ct = 0; ct < 4; ++ct) {
            int col = (wid >> 1) * 64 + ct * 16 + l15;
            int s   = (quad + (col >> 1)) & 3;
            fB[ct] = *(const bf16x8*)&Bls[col * 32 + s * 8];
        }
        #pragma unroll
        for (int rt = 0; rt < 4; ++rt)
            #pragma unroll
            for (int ct = 0; ct < 4; ++ct)
                acc[rt][ct] = __builtin_amdgcn_mfma_f32_16x16x32_bf16(
                                  fA[rt], fB[ct], acc[rt][ct], 0, 0, 0);
        __syncthreads();   // LDS reuse guard
    }

    bf16* Cb = C + (size_t)blockIdx.y * cStride;
    int m0 = gy * 128 + (wid & 1) * 64;
    int n0 = gx * 128 + (wid >> 1) * 64;
    if (!SKEW) {
        #pragma unroll
        for (int rt = 0; rt < 4; ++rt)
            #pragma unroll
            for (int ct = 0; ct < 4; ++ct)
                #pragma unroll
                for (int r = 0; r < 4; ++r) {
                    int m = m0 + rt * 16 + quad * 4 + r;
                    int n = n0 + ct * 16 + l15;
                    Cb[(size_t)m * N + n] = (bf16)acc[rt][ct][r];
                }
    } else {
        #pragma unroll
        for (int rt = 0; rt < 4; ++rt)
            #pragma unroll
            for (int ct = 0; ct < 4; ++ct)
                #pragma unroll
                for (int r = 0; r < 4; ++r) {
                    int row = m0 + rt * 16 + quad * 4 + r;
                    int c   = n0 + ct * 16 + l15;
                    bool lower = (c >= LL - 1 - row);
                    int dr = lower ? row : row - 1;
                    int dc = lower ? c - (LL - 1 - row) : c + row + 1;
                    if (lower || row >= 1)
                        Cb[(size_t)dr * LL + dc] = (bf16)acc[rt][ct][r];
                }
    }
}

// Fused attention, R10: NO K/V LDS staging.  K[b] (1 MB) and the block's
// V-half (1 MB) are L2-resident (64 blocks per XCD share them via the XCD
// pinning), and the MFMA fragment layouts are directly loadable from global
// with full cache-line utilization:
//   kf[ks]     = K[j0+jrow][ks*32+quad*8 ..+8]   (16 rows x 64B/instr)
//   vf[nt][kk] = Vt[dd][j0+kk*32+quad*8 ..+8]    (16 rows x 64B/instr)
// The old global_load_lds path moved the SAME bytes through L2, then added a
// 64KB LDS write + 64KB LDS read per block-iter plus vmcnt choreography
// (guide common-mistake #7: don't LDS-stage L2-fit data).  LDS now holds only
// Ss/Ps/stats (~14 KB).  Two raw lgkm-only s_barriers per iter (Ss handoff,
// Ps handoff) -- they do NOT drain vmcnt, so the vf prefetch (issued before
// b2, consumed after b3) and the 1-ahead srel prefetch stay in flight across
// them.  Hazards: Ss RAW=b2, WAR=b3+program order; Ps/aSt RAW=b3, WAR=next b2.
__launch_bounds__(256, 2)
__global__ void attn_kernel(const bf16* __restrict__ Qw, const bf16* __restrict__ Kw,
                            const bf16* __restrict__ Vt, const bf16* __restrict__ Srel,
                            float* __restrict__ out)
{
    __shared__ float Ss[32][68];
    __shared__ bf16  Ps[32][72];
    __shared__ float mSt[32], lSt[32], aSt[32];

    int tid  = threadIdx.x;
    int lane = tid & 63;
    int wid  = tid >> 6;
    int l15  = lane & 15;
    int quad = lane >> 4;

    int xcd = blockIdx.x & 7;          // XCD = blockIdx % 8 (round-robin dispatch)
    int b   = xcd >> 1;
    int dh  = xcd & 1;
    int i0  = (blockIdx.x >> 3) * 32;

    const bf16* Qb = Qw + (size_t)b * LL * DKK;
    const bf16* Kb = Kw + (size_t)b * LL * DKK;
    const bf16* Sb = Srel + (size_t)b * LL * LL;
    const bf16* Vb = Vt + (size_t)(dh * 256) * (BB * LL) + (size_t)b * LL;

    bf16x8 Qreg[2][8];
    #pragma unroll
    for (int rt = 0; rt < 2; ++rt)
        #pragma unroll
        for (int ks = 0; ks < 8; ++ks)
            Qreg[rt][ks] = *(const bf16x8*)(Qb + (size_t)(i0 + rt * 16 + l15) * DKK
                                            + ks * 32 + quad * 8);

    if (tid < 32) { mSt[tid] = -1e30f; lSt[tid] = 0.f; }

    f32x4 accO[2][4];
    #pragma unroll
    for (int rt = 0; rt < 2; ++rt)
        #pragma unroll
        for (int nt = 0; nt < 4; ++nt) accO[rt][nt] = 0;

    int srow = i0 + (tid >> 3), ssg = tid & 7;
    bf16x8 srelCur = *(const bf16x8*)(Sb + (size_t)srow * LL + ssg * 8);

    int jrow = wid * 16 + l15;

    for (int j0 = 0; j0 < LL; j0 += 64) {
        int jn = j0 + 64;
        bool notlast = (jn < LL);

        // ===== QK phase: direct K fragment loads (L2-resident) =====
        bf16x8 kf[8];
        const bf16* krow = Kb + (size_t)(j0 + jrow) * DKK;
        #pragma unroll
        for (int ks = 0; ks < 8; ++ks)
            kf[ks] = *(const bf16x8*)(krow + ks * 32 + quad * 8);
        // srel(i+1) prefetch: consumed in softmax of NEXT iter (full-iter window)
        bf16x8 srelNext = srelCur;
        if (notlast)
            srelNext = *(const bf16x8*)(Sb + (size_t)srow * LL + jn + ssg * 8);

        f32x4 s0 = 0, s1 = 0;
        __builtin_amdgcn_s_setprio(1);
        #pragma unroll
        for (int ks = 0; ks < 8; ++ks) {
            s0 = __builtin_amdgcn_mfma_f32_16x16x32_bf16(Qreg[0][ks], kf[ks], s0, 0, 0, 0);
            s1 = __builtin_amdgcn_mfma_f32_16x16x32_bf16(Qreg[1][ks], kf[ks], s1, 0, 0, 0);
        }
        __builtin_amdgcn_s_setprio(0);
        #pragma unroll
        for (int r = 0; r < 4; ++r) {
            Ss[quad * 4 + r][wid * 16 + l15]      = s0[r];
            Ss[16 + quad * 4 + r][wid * 16 + l15] = s1[r];
        }

        // ===== vf prefetch: issued before b2, consumed after b3 (latency
        //       spans b2 + softmax + b3) =====
        bf16x8 vf[4][2];
        #pragma unroll
        for (int nt = 0; nt < 4; ++nt) {
            int dd = wid * 64 + nt * 16 + l15;
            const bf16* vrow = Vb + (size_t)dd * (BB * LL) + j0;
            vf[nt][0] = *(const bf16x8*)(vrow + quad * 8);
            vf[nt][1] = *(const bf16x8*)(vrow + 32 + quad * 8);
        }

        asm volatile("s_waitcnt lgkmcnt(0)\ns_barrier" ::: "memory");   // b2: Ss handoff

        // ===== softmax =====
        {
            int r = tid >> 3, sg = tid & 7;
            int i = i0 + r;
            float v[8];
            #pragma unroll
            for (int c = 0; c < 8; ++c) {
                float sr = (j0 + sg * 8 + c == i + 1) ? 0.f : (float)srelCur[c];
                v[c] = (Ss[r][sg * 8 + c] + sr) * 0.0625f;
            }
            float tmax = v[0];
            #pragma unroll
            for (int c = 1; c < 8; ++c) tmax = fmaxf(tmax, v[c]);
            tmax = fmaxf(tmax, __shfl_xor(tmax, 1));
            tmax = fmaxf(tmax, __shfl_xor(tmax, 2));
            tmax = fmaxf(tmax, __shfl_xor(tmax, 4));
            float mOld = mSt[r], lOld = lSt[r];
            float mNew = fmaxf(mOld, tmax);
            float alpha = __expf(mOld - mNew);
            float ps = 0.f;
            bf16x8 pv;
            #pragma unroll
            for (int c = 0; c < 8; ++c) {
                float p = __expf(v[c] - mNew);
                ps += p;
                pv[c] = (bf16)p;
            }
            ps += __shfl_xor(ps, 1);
            ps += __shfl_xor(ps, 2);
            ps += __shfl_xor(ps, 4);
            *(bf16x8*)&Ps[r][sg * 8] = pv;
            if (sg == 0) { mSt[r] = mNew; lSt[r] = alpha * lOld + ps; aSt[r] = alpha; }
        }
        srelCur = srelNext;
        asm volatile("s_waitcnt lgkmcnt(0)\ns_barrier" ::: "memory");   // b3: Ps handoff

        // ===== PV phase (vf already in regs; compiler waits vmcnt here) =====
        bf16x8 aF[2][2];
        #pragma unroll
        for (int rt = 0; rt < 2; ++rt)
            #pragma unroll
            for (int kk = 0; kk < 2; ++kk)
                aF[rt][kk] = *(const bf16x8*)&Ps[rt * 16 + l15][kk * 32 + quad * 8];
        float ar[2][4];
        #pragma unroll
        for (int rt = 0; rt < 2; ++rt)
            #pragma unroll
            for (int r = 0; r < 4; ++r) ar[rt][r] = aSt[rt * 16 + quad * 4 + r];
        __builtin_amdgcn_s_setprio(1);
        #pragma unroll
        for (int nt = 0; nt < 4; ++nt) {
            #pragma unroll
            for (int rt = 0; rt < 2; ++rt) {
                f32x4 o = accO[rt][nt];
                o[0] *= ar[rt][0]; o[1] *= ar[rt][1];
                o[2] *= ar[rt][2]; o[3] *= ar[rt][3];
                o = __builtin_amdgcn_mfma_f32_16x16x32_bf16(aF[rt][0], vf[nt][0], o, 0, 0, 0);
                o = __builtin_amdgcn_mfma_f32_16x16x32_bf16(aF[rt][1], vf[nt][1], o, 0, 0, 0);
                accO[rt][nt] = o;
            }
        }
        __builtin_amdgcn_s_setprio(0);
        // no trailing barrier: Ss WAR covered by b3(i), Ps/aSt WAR by b2(i+1)
    }
    float lr[2][4];
    #pragma unroll
    for (int rt = 0; rt < 2; ++rt)
        #pragma unroll
        for (int r = 0; r < 4; ++r) lr[rt][r] = 1.f / lSt[rt * 16 + quad * 4 + r];
    #pragma unroll
    for (int rt = 0; rt < 2; ++rt)
        #pragma unroll
        for (int nt = 0; nt < 4; ++nt)
            #pragma unroll
            for (int r = 0; r < 4; ++r) {
                int i = i0 + rt * 16 + quad * 4 + r;
                int d = dh * 256 + wid * 64 + nt * 16 + l15;
                out[((size_t)b * LL + i) * DD + d] = accO[rt][nt][r] * lr[rt][r];
            }
}

extern "C" void kernel_launch(void* const* d_in, const int* in_sizes, int n_in,
                              void* d_out, int out_size, void* d_ws, size_t ws_size,
                              hipStream_t stream) {
    const float* inQ = (const float*)d_in[0];
    const float* inK = (const float*)d_in[1];
    const float* inV = (const float*)d_in[2];
    const float* Wq  = (const float*)d_in[3];
    const float* Wk  = (const float*)d_in[4];
    const float* Wv  = (const float*)d_in[5];
    const float* E   = (const float*)d_in[6];
    float* out = (float*)d_out;

    char* ws = (char*)d_ws;
    bf16* Qw   = (bf16*)(ws);                         // 4 MB  [B*L][DK]
    bf16* Kw   = (bf16*)(ws + ((size_t)4  << 20));    // 4 MB  [B*L][DK]
    bf16* Vt   = (bf16*)(ws + ((size_t)8  << 20));    // 8 MB  [D][B*L]
    bf16* SrelW= (bf16*)(ws + ((size_t)16 << 20));    // 32 MB [B,L,L] skewed
    // transient buffers inside the Srel region (dead before QE writes Srel):
    bf16* Xq   = (bf16*)(ws + ((size_t)16 << 20));    // 8 MB  inQ as bf16
    bf16* Xk   = (bf16*)(ws + ((size_t)24 << 20));    // 8 MB
    bf16* Xv   = (bf16*)(ws + ((size_t)32 << 20));    // 8 MB
    bf16* Vw   = (bf16*)(ws + ((size_t)40 << 20));    // 8 MB  V row-major
    bf16* WqT  = (bf16*)(ws + ((size_t)48 << 20));            // [DK][D]
    bf16* WkT  = (bf16*)(ws + ((size_t)48 << 20) + 262144);   // [DK][D]
    bf16* WvT  = (bf16*)(ws + ((size_t)48 << 20) + 524288);   // [D][D]
    bf16* Eb   = (bf16*)(ws + ((size_t)49 << 20));            // [L][DK]

    conv3_f32_bf16<<<dim3(4096, 3), 256, 0, stream>>>(inQ, inK, inV, Xq, Xk, Xv,
                                                      (BB * LL * DD) / 4);
    conv_f32_bf16v<<<512,  256, 0, stream>>>(E, Eb, (LL * DKK) / 4);
    transpose_f32_bf16<<<512,  256, 0, stream>>>(Wq, WqT, DD, DKK);
    transpose_f32_bf16<<<512,  256, 0, stream>>>(Wk, WkT, DD, DKK);
    transpose_f32_bf16<<<1024, 256, 0, stream>>>(Wv, WvT, DD, DD);

    // Q = Xq·Wq^T' and K = Xk·Wk^T' fused via blockIdx.y: M=8192 N=256 K=512
    gemm128<0><<<dim3(2 * 64, 2),  256, 0, stream>>>(Xq, WqT, Qw, DKK, DD,
                                                     4194304L, 131072L, 2097152L);
    // Vw = Xv·Wv^T': M=8192 N=512 K=512
    gemm128<0><<<dim3(4 * 64, 1),  256, 0, stream>>>(Xv, WvT, Vw, DD, DD, 0, 0, 0);
    // Vt = Vw^T  [512][8192]
    transpose_bf16_tile<<<(DD / 64) * (BB * LL / 64), 256, 0, stream>>>(Vw, Vt, BB * LL, DD);
    // Srel (skewed) = skew(Q·E^T): per-batch M=N=2048 K=256
    gemm128<1><<<dim3(16 * 16, BB), 256, 0, stream>>>(Qw, Eb, SrelW, LL, DKK,
                                                      (long)LL * DKK, 0, (long)LL * LL);
    attn_kernel<<<dim3(BB * 64 * 2), 256, 0, stream>>>(Qw, Kw, Vt, SrelW, out);
}